// Round 3
// baseline (118.373 us; speedup 1.0000x reference)
//
#include <hip/hip_runtime.h>

#define T0 4096
#define N1 2051          // level-1 output length
#define NLEV 5
#define BLOCK 256
#define PAD 6            // left pad; right pad is 7

// filters reversed so tap k multiplies ext[2i+k]  (rLO[k] = DEC_LO[7-k])
#define RLO0  0.23037781330885523f
#define RLO1  0.7148465705525415f
#define RLO2  0.6308807679295904f
#define RLO3 -0.02798376941698385f
#define RLO4 -0.18703481171888114f
#define RLO5  0.030841381835986965f
#define RLO6  0.032883011666982945f
#define RLO7 -0.010597401784997278f

#define RHI0 -0.010597401784997278f
#define RHI1 -0.032883011666982945f
#define RHI2  0.030841381835986965f
#define RHI3  0.18703481171888114f
#define RHI4 -0.02798376941698385f
#define RHI5 -0.6308807679295904f
#define RHI6  0.7148465705525415f
#define RHI7 -0.23037781330885523f

__device__ __forceinline__ int symidx(int t, int L) {
    t = (t < 0) ? (-1 - t) : t;
    t = (t >= L) ? (2 * L - 1 - t) : t;
    return t;
}

__device__ __forceinline__ void filt8(const float* __restrict__ t,
                                      float& lo, float& hi) {
    lo = RLO0 * t[0];            hi = RHI0 * t[0];
    lo = fmaf(RLO1, t[1], lo);   hi = fmaf(RHI1, t[1], hi);
    lo = fmaf(RLO2, t[2], lo);   hi = fmaf(RHI2, t[2], hi);
    lo = fmaf(RLO3, t[3], lo);   hi = fmaf(RHI3, t[3], hi);
    lo = fmaf(RLO4, t[4], lo);   hi = fmaf(RHI4, t[4], hi);
    lo = fmaf(RLO5, t[5], lo);   hi = fmaf(RHI5, t[5], hi);
    lo = fmaf(RLO6, t[6], lo);   hi = fmaf(RHI6, t[6], hi);
    lo = fmaf(RLO7, t[7], lo);   hi = fmaf(RHI7, t[7], hi);
}

__global__ __launch_bounds__(BLOCK) void dwt5_kernel(
    const float* __restrict__ x, float* __restrict__ out,
    long long offA, long long offD1, long long offD2, long long offD3,
    long long offD4, long long offD5)
{
    // padded level buffers: ext[PAD + s] = sample s
    __shared__ float extB[N1 + 16];    // level-1 approx (2051)
    __shared__ float extC[1029 + 16];  // ping-pong for levels 2..5

    const int row = blockIdx.x;
    const int tid = threadIdx.x;
    const float* __restrict__ xrow = x + (size_t)row * T0;

    // ---- level 1: taps straight from global (L1-cached), no input staging ----
    {
        float* __restrict__ dSeg = out + offD1 + (long long)row * N1;
        for (int i = tid; i < N1; i += BLOCK) {
            float t[8];
            if (i >= 3 && i <= 2047) {          // interior: direct loads
                const float* __restrict__ p = xrow + 2 * i - 6;
#pragma unroll
                for (int k = 0; k < 8; ++k) t[k] = p[k];
            } else {                            // boundary: reflected loads
#pragma unroll
                for (int k = 0; k < 8; ++k) t[k] = xrow[symidx(2 * i - 6 + k, T0)];
            }
            float lo, hi;
            filt8(t, lo, hi);
            __builtin_nontemporal_store(hi, &dSeg[i]);
            extB[PAD + i] = lo;
            if (i < 6)        extB[5 - i] = lo;                  // left mirror
            if (i >= N1 - 7)  extB[PAD + N1 + (N1 - 1 - i)] = lo; // right mirror
        }
    }
    __syncthreads();

    // ---- levels 2..5 from LDS ----
    const long long dOff[4] = {offD2, offD3, offD4, offD5};
    float* src = extB;
    float* dst = extC;
    int L = N1;
#pragma unroll
    for (int lev = 0; lev < 4; ++lev) {
        const int nOut = (L + 7) >> 1;
        float* __restrict__ dSeg = out + dOff[lev] + (long long)row * nOut;
        float* __restrict__ aSeg = out + offA + (long long)row * nOut;
        const float2* __restrict__ e2 = reinterpret_cast<const float2*>(src);
        for (int i = tid; i < nOut; i += BLOCK) {
            const float2 w0 = e2[i + 0];
            const float2 w1 = e2[i + 1];
            const float2 w2 = e2[i + 2];
            const float2 w3 = e2[i + 3];
            const float t[8] = {w0.x, w0.y, w1.x, w1.y, w2.x, w2.y, w3.x, w3.y};
            float lo, hi;
            filt8(t, lo, hi);
            __builtin_nontemporal_store(hi, &dSeg[i]);
            if (lev == 3) {
                __builtin_nontemporal_store(lo, &aSeg[i]);
            } else {
                dst[PAD + i] = lo;
                if (i < 6)         dst[5 - i] = lo;
                if (i >= nOut - 7) dst[PAD + nOut + (nOut - 1 - i)] = lo;
            }
        }
        __syncthreads();
        float* tmp = src; src = dst; dst = tmp;
        L = nOut;
    }
}

extern "C" void kernel_launch(void* const* d_in, const int* in_sizes, int n_in,
                              void* d_out, int out_size, void* d_ws, size_t ws_size,
                              hipStream_t stream) {
    const float* x = (const float*)d_in[0];
    float* out = (float*)d_out;

    const int rows = in_sizes[0] / T0;   // 64*64 = 4096
    const int n1 = (T0 + 7) / 2;         // 2051
    const int n2 = (n1 + 7) / 2;         // 1029
    const int n3 = (n2 + 7) / 2;         // 518
    const int n4 = (n3 + 7) / 2;         // 262
    const int n5 = (n4 + 7) / 2;         // 134

    const long long offA  = 0;
    const long long offD5 = offA  + (long long)rows * n5;
    const long long offD4 = offD5 + (long long)rows * n5;
    const long long offD3 = offD4 + (long long)rows * n4;
    const long long offD2 = offD3 + (long long)rows * n3;
    const long long offD1 = offD2 + (long long)rows * n2;

    dwt5_kernel<<<rows, BLOCK, 0, stream>>>(x, out, offA, offD1, offD2, offD3,
                                            offD4, offD5);
}